// Round 14
// baseline (356.843 us; speedup 1.0000x reference)
//
#include <hip/hip_runtime.h>
#include <hip/hip_bf16.h>
#include <math.h>

#define NT 365
#define NGRID 30000
#define NX 16
#define HID 256
#define CB 16   // cells per wave

typedef __attribute__((ext_vector_type(8))) short bf16x8;
typedef __attribute__((ext_vector_type(4))) float f32x4;

static __device__ __forceinline__ unsigned cvt_pk(float lo, float hi) {
    unsigned r;
    asm("v_cvt_pk_bf16_f32 %0, %1, %2" : "=v"(r) : "v"(lo), "v"(hi));
    return r;
}
union BF8 { bf16x8 v; unsigned u[4]; };
static __device__ __forceinline__ short f2bf(float f) {   // setup only
    return __builtin_bit_cast(short, __float2bfloat16(f));
}

// Pre-kernel: w_eff = Wo@Wh (256), b_eff = Wo@bh + bo (scalar).
__global__ void weff_kernel(const float* __restrict__ Wh, const float* __restrict__ Wo,
                            const float* __restrict__ bh, const float* __restrict__ bo,
                            float* __restrict__ ws) {
    int h = threadIdx.x;  // 256 threads
    float acc = 0.f;
    for (int j = 0; j < HID; ++j)
        acc = fmaf(Wo[j], Wh[j * HID + h], acc);
    ws[h] = acc;

    __shared__ float prod[HID];
    prod[h] = Wo[h] * bh[h];
    __syncthreads();
    if (h == 0) {
        float b = bo[0];
        for (int j = 0; j < HID; ++j) b += prod[j];
        ws[HID] = b;
    }
}

// One timestep, fused pipeline (r10/r13 structure, verbatim): per ks-pair
// {2x MFMA1 -> relu/pack -> MFMA2}, only 8 accumulator floats live at once.
// Fused compute region at wave priority 1 (T5, +8% measured r13).
__device__ __forceinline__ void rnn_step(
    int t, int tpre, bool tail,
    const float* __restrict__ x, const float* __restrict__ yb, float* __restrict__ ob,
    size_t xoff, int hi, int lane,
    const bf16x8* a1, const bf16x8* a2, const f32x4& beff4, const f32x4& z4,
    float4& xaS, float4& xbS, float& yoS,
    const float4& xaO, const float4& xbO,
    unsigned* px, float& yprev)
{
    const float yo = yoS;
    const float y_in = (yo == yo) ? yo : yprev;         // fillObs

    // b1: zeros flow from permanently-zero x regs on hi>=2 lanes
    BF8 b1;
    const unsigned py = cvt_pk(y_in, 1.0f);             // y slot + bias column
    b1.u[0] = (hi == 2) ? py : px[0];
    b1.u[1] = px[1]; b1.u[2] = px[2]; b1.u[3] = px[3];

    if (!tail) {
        // issue next-slot loads early (hide HBM latency under this step's MFMAs)
        if (hi < 2) {
            const float4* p = (const float4*)(x + (size_t)tpre * (NGRID * NX) + xoff);
            xaS = p[0]; xbS = p[1];
        }
        yoS = yb[(size_t)tpre * NGRID];
        // prepack next step's x-fragment from the other slot (off the serial chain)
        px[0] = cvt_pk(xaO.x, xaO.y);
        px[1] = cvt_pk(xaO.z, xaO.w);
        px[2] = cvt_pk(xbO.x, xbO.y);
        px[3] = cvt_pk(xbO.z, xbO.w);
    }

    // fused hidden + output projection: 4 independent 2-deep MFMA2 chains
    __builtin_amdgcn_s_setprio(1);
    f32x4 acc2[4] = {beff4, z4, z4, z4};
#pragma unroll
    for (int ks = 0; ks < 8; ++ks) {
        const f32x4 e = __builtin_amdgcn_mfma_f32_16x16x32_bf16(a1[2 * ks],     b1.v, z4, 0, 0, 0);
        const f32x4 o = __builtin_amdgcn_mfma_f32_16x16x32_bf16(a1[2 * ks + 1], b1.v, z4, 0, 0, 0);
        BF8 b2;
        b2.u[0] = cvt_pk(fmaxf(e[0], 0.f), fmaxf(e[1], 0.f));
        b2.u[1] = cvt_pk(fmaxf(e[2], 0.f), fmaxf(e[3], 0.f));
        b2.u[2] = cvt_pk(fmaxf(o[0], 0.f), fmaxf(o[1], 0.f));
        b2.u[3] = cvt_pk(fmaxf(o[2], 0.f), fmaxf(o[3], 0.f));
        acc2[ks & 3] = __builtin_amdgcn_mfma_f32_16x16x32_bf16(a2[ks], b2.v, acc2[ks & 3], 0, 0, 0);
    }
    __builtin_amdgcn_s_setprio(0);

    const float ynew = (acc2[0][0] + acc2[1][0]) + (acc2[2][0] + acc2[3][0]);
    if (lane < 16) ob[(size_t)t * NGRID] = ynew;     // broadcast in every lane
    yprev = ynew;
}

// One wave = 16 cells, no barriers/shuffles, time unrolled x2 with two static
// prefetch buffer slots. MFMA-1 hidden (rows permuted so C-output is MFMA-2's
// B fragment); MFMA-2 A = w_eff broadcast rows -> scalar broadcast to all lanes.
__global__ __launch_bounds__(64, 2) void rnn_u2(
    const float* __restrict__ x,   // (NT, NGRID, NX)
    const float* __restrict__ y,   // (NT, NGRID, 1), NaN = missing
    const float* __restrict__ Wi,  // (HID, NX+1)
    const float* __restrict__ bi,  // (HID)
    const float* __restrict__ ws,  // w_eff[256], b_eff
    float* __restrict__ out)       // (NT, NGRID, 1)
{
    const int lane = threadIdx.x & 63;
    const int c    = lane & 15;
    const int hi   = lane >> 4;
    const int cell0 = blockIdx.x * CB;

    // De-phase co-resident waves: 1-wave blocks run byte-identical streams at
    // identical rates -> phase-locked stall windows leave the SIMD idle
    // (~1200 cyc/step measured gap between wall and issue). One-time start
    // offset of (blockIdx&7) x ~192 cyc breaks the convoy; cost ~0.03%.
    {
        const int ph = blockIdx.x & 7;
        for (int i = 0; i < ph; ++i) __builtin_amdgcn_s_sleep(3);
    }

    // ---- A1 fragments (Wi rows permuted h(m,i)=32(m>>1)+8(i>>2)+4(m&1)+(i&3)) ----
    bf16x8 a1[16];
#pragma unroll
    for (int m = 0; m < 16; ++m) {
        const int h = 32 * (m >> 1) + 8 * (c >> 2) + 4 * (m & 1) + (c & 3);
        const float* wrow = Wi + h * (NX + 1);
        bf16x8 av;
        if (hi < 2) {
#pragma unroll
            for (int j = 0; j < 8; ++j) av[j] = f2bf(wrow[hi * 8 + j]);
        } else if (hi == 2) {
            av[0] = f2bf(wrow[16]);    // k=16: weight on y_in
            av[1] = f2bf(bi[h]);       // k=17: bias (x const 1.0)
#pragma unroll
            for (int j = 2; j < 8; ++j) av[j] = 0;
        } else {
#pragma unroll
            for (int j = 0; j < 8; ++j) av[j] = 0;
        }
        a1[m] = av;
    }

    // ---- A2: w_eff, same value in all 16 rows ----
    bf16x8 a2[8];
#pragma unroll
    for (int ks = 0; ks < 8; ++ks) {
        bf16x8 av;
#pragma unroll
        for (int j = 0; j < 8; ++j) av[j] = f2bf(ws[32 * ks + 8 * hi + j]);
        a2[ks] = av;
    }
    const float b_eff = ws[HID];
    const f32x4 z4 = {0.f, 0.f, 0.f, 0.f};
    const f32x4 beff4 = {b_eff, b_eff, b_eff, b_eff};

    const size_t xoff = (size_t)(cell0 + c) * NX + hi * 8;
    const float* yb = y + cell0 + c;
    float*       ob = out + cell0 + c;

    // ---- two buffer slots: slot0 <- t=0, slot1 <- t=1 ----
    float4 xa0 = {0,0,0,0}, xb0 = {0,0,0,0};
    float4 xa1 = {0,0,0,0}, xb1 = {0,0,0,0};
    if (hi < 2) {
        const float4* p0 = (const float4*)(x + xoff);
        xa0 = p0[0]; xb0 = p0[1];
        const float4* p1 = (const float4*)(x + (size_t)(NGRID * NX) + xoff);
        xa1 = p1[0]; xb1 = p1[1];
    }
    float yo0 = yb[0];
    float yo1 = yb[NGRID];
    float yprev = 0.f;

    // prepack step-0 x-fragment (hi>=2 lanes: zeros flow through cvt_pk)
    unsigned px[4];
    px[0] = cvt_pk(xa0.x, xa0.y);
    px[1] = cvt_pk(xa0.z, xa0.w);
    px[2] = cvt_pk(xb0.x, xb0.y);
    px[3] = cvt_pk(xb0.z, xb0.w);

    for (int t = 0; t < NT - 1; t += 2) {
        const int tp0 = (t + 2 < NT) ? t + 2 : NT - 1;
        const int tp1 = (t + 3 < NT) ? t + 3 : NT - 1;
        rnn_step(t,     tp0, false, x, yb, ob, xoff, hi, lane, a1, a2, beff4, z4,
                 xa0, xb0, yo0, xa1, xb1, px, yprev);
        rnn_step(t + 1, tp1, false, x, yb, ob, xoff, hi, lane, a1, a2, beff4, z4,
                 xa1, xb1, yo1, xa0, xb0, px, yprev);
    }
    // final step t = NT-1 = 364 (slot0 parity), no prefetch/prepack
    rnn_step(NT - 1, NT - 1, true, x, yb, ob, xoff, hi, lane, a1, a2, beff4, z4,
             xa0, xb0, yo0, xa1, xb1, px, yprev);
}

extern "C" void kernel_launch(void* const* d_in, const int* in_sizes, int n_in,
                              void* d_out, int out_size, void* d_ws, size_t ws_size,
                              hipStream_t stream) {
    const float* x  = (const float*)d_in[0];
    const float* y  = (const float*)d_in[1];
    const float* Wi = (const float*)d_in[2];
    const float* bi = (const float*)d_in[3];
    const float* Wh = (const float*)d_in[4];
    const float* bh = (const float*)d_in[5];
    const float* Wo = (const float*)d_in[6];
    const float* bo = (const float*)d_in[7];
    float* out = (float*)d_out;
    float* ws  = (float*)d_ws;

    weff_kernel<<<1, HID, 0, stream>>>(Wh, Wo, bh, bo, ws);
    rnn_u2<<<NGRID / CB, 64, 0, stream>>>(x, y, Wi, bi, ws, out);
}

// Round 16
// 328.014 us; speedup vs baseline: 1.0879x; 1.0879x over previous
//
#include <hip/hip_runtime.h>
#include <hip/hip_bf16.h>
#include <math.h>

#define NT 365
#define NGRID 30000
#define NX 16
#define HID 256
#define CB 16   // cells per wave

typedef __attribute__((ext_vector_type(8))) short bf16x8;
typedef __attribute__((ext_vector_type(4))) float f32x4;
typedef __attribute__((ext_vector_type(2))) short s16x2;

static __device__ __forceinline__ unsigned cvt_pk(float lo, float hi) {
    unsigned r;
    asm("v_cvt_pk_bf16_f32 %0, %1, %2" : "=v"(r) : "v"(lo), "v"(hi));
    return r;
}
union BF8 { bf16x8 v; unsigned u[4]; };
static __device__ __forceinline__ short f2bf(float f) {   // setup only
    return __builtin_bit_cast(short, __float2bfloat16(f));
}

// Convert a pair of f32 (MFMA outputs) to packed bf16 and apply ReLU on the
// packed halves. ALL compiler-visible ops: __float2bfloat16 pairs lower to
// v_cvt_pk_bf16_f32 (r5 evidence) and elementwise_max on short2 lowers to
// v_pk_max_i16 — so MFMA->consumer hazard nops are inserted correctly
// (inline asm reading MFMA results directly is NOT hazard-protected; r15 NaN).
// ReLU-after-round is exact: positive bf16 orders like positive int16;
// negative/−0 halves have the int16 sign bit set -> max_i16(x,0) zeroes them.
static __device__ __forceinline__ unsigned relu_cvt(float lo, float hi) {
    const unsigned u =
        ((unsigned)(unsigned short)__builtin_bit_cast(unsigned short, __float2bfloat16(hi)) << 16) |
        (unsigned)(unsigned short)__builtin_bit_cast(unsigned short, __float2bfloat16(lo));
    s16x2 v = __builtin_bit_cast(s16x2, u);
    const s16x2 z = {0, 0};
    v = __builtin_elementwise_max(v, z);
    return __builtin_bit_cast(unsigned, v);
}

// Pre-kernel: w_eff = Wo@Wh (256), b_eff = Wo@bh + bo (scalar).
__global__ void weff_kernel(const float* __restrict__ Wh, const float* __restrict__ Wo,
                            const float* __restrict__ bh, const float* __restrict__ bo,
                            float* __restrict__ ws) {
    int h = threadIdx.x;  // 256 threads
    float acc = 0.f;
    for (int j = 0; j < HID; ++j)
        acc = fmaf(Wo[j], Wh[j * HID + h], acc);
    ws[h] = acc;

    __shared__ float prod[HID];
    prod[h] = Wo[h] * bh[h];
    __syncthreads();
    if (h == 0) {
        float b = bo[0];
        for (int j = 0; j < HID; ++j) b += prod[j];
        ws[HID] = b;
    }
}

// One timestep, fused pipeline (r13 structure): per ks-pair
// {2x MFMA1 -> relu_cvt pack -> MFMA2}, 8 accumulator floats live at once.
// Fused compute region at wave priority 1 (T5, +8% measured r13).
__device__ __forceinline__ void rnn_step(
    int t, int tpre, bool tail,
    const float* __restrict__ x, const float* __restrict__ yb, float* __restrict__ ob,
    size_t xoff, int hi, int lane,
    const bf16x8* a1, const bf16x8* a2, const f32x4& beff4, const f32x4& z4,
    float4& xaS, float4& xbS, float& yoS,
    const float4& xaO, const float4& xbO,
    unsigned* px, float& yprev)
{
    const float yo = yoS;
    const float y_in = (yo == yo) ? yo : yprev;         // fillObs

    // b1: zeros flow from permanently-zero x regs on hi>=2 lanes
    BF8 b1;
    const unsigned py = cvt_pk(y_in, 1.0f);             // y slot + bias column
    b1.u[0] = (hi == 2) ? py : px[0];
    b1.u[1] = px[1]; b1.u[2] = px[2]; b1.u[3] = px[3];

    if (!tail) {
        // issue next-slot loads early (hide HBM latency under this step's MFMAs)
        if (hi < 2) {
            const float4* p = (const float4*)(x + (size_t)tpre * (NGRID * NX) + xoff);
            xaS = p[0]; xbS = p[1];
        }
        yoS = yb[(size_t)tpre * NGRID];
        // prepack next step's x-fragment from the other slot (off the serial chain)
        px[0] = cvt_pk(xaO.x, xaO.y);
        px[1] = cvt_pk(xaO.z, xaO.w);
        px[2] = cvt_pk(xbO.x, xbO.y);
        px[3] = cvt_pk(xbO.z, xbO.w);
    }

    // fused hidden + output projection: 4 independent 2-deep MFMA2 chains
    __builtin_amdgcn_s_setprio(1);
    f32x4 acc2[4] = {beff4, z4, z4, z4};
#pragma unroll
    for (int ks = 0; ks < 8; ++ks) {
        const f32x4 e = __builtin_amdgcn_mfma_f32_16x16x32_bf16(a1[2 * ks],     b1.v, z4, 0, 0, 0);
        const f32x4 o = __builtin_amdgcn_mfma_f32_16x16x32_bf16(a1[2 * ks + 1], b1.v, z4, 0, 0, 0);
        BF8 b2;
        b2.u[0] = relu_cvt(e[0], e[1]);
        b2.u[1] = relu_cvt(e[2], e[3]);
        b2.u[2] = relu_cvt(o[0], o[1]);
        b2.u[3] = relu_cvt(o[2], o[3]);
        acc2[ks & 3] = __builtin_amdgcn_mfma_f32_16x16x32_bf16(a2[ks], b2.v, acc2[ks & 3], 0, 0, 0);
    }
    __builtin_amdgcn_s_setprio(0);

    const float ynew = (acc2[0][0] + acc2[1][0]) + (acc2[2][0] + acc2[3][0]);
    if (lane < 16) ob[(size_t)t * NGRID] = ynew;     // broadcast in every lane
    yprev = ynew;
}

// One wave = 16 cells, no barriers/shuffles, time unrolled x2 with two static
// prefetch buffer slots. MFMA-1 hidden (rows permuted so C-output is MFMA-2's
// B fragment); MFMA-2 A = w_eff broadcast rows -> scalar broadcast to all lanes.
// launch_bounds(64,2): the min-waves metadata also caps residency (r6/r9).
__global__ __launch_bounds__(64, 2) void rnn_u2(
    const float* __restrict__ x,   // (NT, NGRID, NX)
    const float* __restrict__ y,   // (NT, NGRID, 1), NaN = missing
    const float* __restrict__ Wi,  // (HID, NX+1)
    const float* __restrict__ bi,  // (HID)
    const float* __restrict__ ws,  // w_eff[256], b_eff
    float* __restrict__ out)       // (NT, NGRID, 1)
{
    const int lane = threadIdx.x & 63;
    const int c    = lane & 15;
    const int hi   = lane >> 4;
    const int cell0 = blockIdx.x * CB;

    // ---- A1 fragments (Wi rows permuted h(m,i)=32(m>>1)+8(i>>2)+4(m&1)+(i&3)) ----
    bf16x8 a1[16];
#pragma unroll
    for (int m = 0; m < 16; ++m) {
        const int h = 32 * (m >> 1) + 8 * (c >> 2) + 4 * (m & 1) + (c & 3);
        const float* wrow = Wi + h * (NX + 1);
        bf16x8 av;
        if (hi < 2) {
#pragma unroll
            for (int j = 0; j < 8; ++j) av[j] = f2bf(wrow[hi * 8 + j]);
        } else if (hi == 2) {
            av[0] = f2bf(wrow[16]);    // k=16: weight on y_in
            av[1] = f2bf(bi[h]);       // k=17: bias (x const 1.0)
#pragma unroll
            for (int j = 2; j < 8; ++j) av[j] = 0;
        } else {
#pragma unroll
            for (int j = 0; j < 8; ++j) av[j] = 0;
        }
        a1[m] = av;
    }

    // ---- A2: w_eff, same value in all 16 rows ----
    bf16x8 a2[8];
#pragma unroll
    for (int ks = 0; ks < 8; ++ks) {
        bf16x8 av;
#pragma unroll
        for (int j = 0; j < 8; ++j) av[j] = f2bf(ws[32 * ks + 8 * hi + j]);
        a2[ks] = av;
    }
    const float b_eff = ws[HID];
    const f32x4 z4 = {0.f, 0.f, 0.f, 0.f};
    const f32x4 beff4 = {b_eff, b_eff, b_eff, b_eff};

    const size_t xoff = (size_t)(cell0 + c) * NX + hi * 8;
    const float* yb = y + cell0 + c;
    float*       ob = out + cell0 + c;

    // ---- two buffer slots: slot0 <- t=0, slot1 <- t=1 ----
    float4 xa0 = {0,0,0,0}, xb0 = {0,0,0,0};
    float4 xa1 = {0,0,0,0}, xb1 = {0,0,0,0};
    if (hi < 2) {
        const float4* p0 = (const float4*)(x + xoff);
        xa0 = p0[0]; xb0 = p0[1];
        const float4* p1 = (const float4*)(x + (size_t)(NGRID * NX) + xoff);
        xa1 = p1[0]; xb1 = p1[1];
    }
    float yo0 = yb[0];
    float yo1 = yb[NGRID];
    float yprev = 0.f;

    // prepack step-0 x-fragment (hi>=2 lanes: zeros flow through cvt_pk)
    unsigned px[4];
    px[0] = cvt_pk(xa0.x, xa0.y);
    px[1] = cvt_pk(xa0.z, xa0.w);
    px[2] = cvt_pk(xb0.x, xb0.y);
    px[3] = cvt_pk(xb0.z, xb0.w);

    for (int t = 0; t < NT - 1; t += 2) {
        const int tp0 = (t + 2 < NT) ? t + 2 : NT - 1;
        const int tp1 = (t + 3 < NT) ? t + 3 : NT - 1;
        rnn_step(t,     tp0, false, x, yb, ob, xoff, hi, lane, a1, a2, beff4, z4,
                 xa0, xb0, yo0, xa1, xb1, px, yprev);
        rnn_step(t + 1, tp1, false, x, yb, ob, xoff, hi, lane, a1, a2, beff4, z4,
                 xa1, xb1, yo1, xa0, xb0, px, yprev);
    }
    // final step t = NT-1 = 364 (slot0 parity), no prefetch/prepack
    rnn_step(NT - 1, NT - 1, true, x, yb, ob, xoff, hi, lane, a1, a2, beff4, z4,
             xa0, xb0, yo0, xa1, xb1, px, yprev);
}

extern "C" void kernel_launch(void* const* d_in, const int* in_sizes, int n_in,
                              void* d_out, int out_size, void* d_ws, size_t ws_size,
                              hipStream_t stream) {
    const float* x  = (const float*)d_in[0];
    const float* y  = (const float*)d_in[1];
    const float* Wi = (const float*)d_in[2];
    const float* bi = (const float*)d_in[3];
    const float* Wh = (const float*)d_in[4];
    const float* bh = (const float*)d_in[5];
    const float* Wo = (const float*)d_in[6];
    const float* bo = (const float*)d_in[7];
    float* out = (float*)d_out;
    float* ws  = (float*)d_ws;

    weff_kernel<<<1, HID, 0, stream>>>(Wh, Wo, bh, bo, ws);
    rnn_u2<<<NGRID / CB, 64, 0, stream>>>(x, y, Wi, bi, ws, out);
}